// Round 1
// baseline (453.270 us; speedup 1.0000x reference)
//
#include <hip/hip_runtime.h>

namespace {

constexpr int KFS = 51;
constexpr int NB = 2, NC = 3, HH = 512, WW = 512;
constexpr int HP = HH + KFS - 1;   // 562
constexpr int WP = WW + KFS - 1;   // 562
constexpr int TW = 128;            // output tile width
constexpr int TH = 8;              // output tile height
constexpr int PX = 4;              // pixels per thread along x
constexpr int NTX = TW / PX;       // 32 threads along x
constexpr int NTHREADS = NTX * TH; // 256
constexpr int RB = TH + 2;         // rolling buffer rows (10)
constexpr int TILEW = TW + KFS - 1;  // 178 valid cols
constexpr int LDSW = 180;            // padded to multiple of 4 floats
constexpr int NROWS = TH + KFS - 1;  // 58 input rows per tile

typedef float lds_t[NC][RB][LDSW];

__device__ __forceinline__ void stage_load(const float* __restrict__ in1b, int rn,
                                           int y0t, int x0t, int t, float sv[3]) {
  const int row = y0t + rn;
  #pragma unroll
  for (int k = 0; k < 3; ++k) {
    const int e = t + k * NTHREADS;
    if (e < NC * TILEW) {
      const int c = e / TILEW;
      const int col = e - c * TILEW;
      sv[k] = in1b[((size_t)c * HP + row) * WP + x0t + col];
    }
  }
}

__device__ __forceinline__ void stage_store(lds_t& tile, int slot, int t, const float sv[3]) {
  #pragma unroll
  for (int k = 0; k < 3; ++k) {
    const int e = t + k * NTHREADS;
    if (e < NC * TILEW) {
      const int c = e / TILEW;
      const int col = e - c * TILEW;
      tile[c][slot][col] = sv[k];
    }
  }
}

// One pass over taps j = JC .. JC+J-1, with the h-chunk held in registers.
template <int JC, int J>
__device__ __forceinline__ void run_pass(lds_t& tile, const float* __restrict__ in1b,
                                         const float* __restrict__ v2,
                                         const float* __restrict__ h3,
                                         float (&acc)[NC][PX],
                                         int y, int x0, int y0t, int x0t, int tx, int ty, int t) {
  // Prologue: stage input rows 0..RB-2 (tile-relative) into the rolling buffer.
  for (int r = 0; r < RB - 1; ++r) {
    float sv[3];
    stage_load(in1b, r, y0t, x0t, t, sv);
    stage_store(tile, r, t, sv);  // slot == r for r < RB
  }
  __syncthreads();

  // h chunk for this thread's 4 pixels: h4[j] = h3[JC+j, y, x0..x0+3]
  float4 h4[J];
  #pragma unroll
  for (int j = 0; j < J; ++j)
    h4[j] = *reinterpret_cast<const float4*>(h3 + ((size_t)(JC + j) * HH + y) * WW + x0);

  int rdslot = ty;            // (ty + i) % RB
  int stslot = RB - 1;        // (i + RB - 1) % RB

  #pragma unroll 1
  for (int i = 0; i < KFS; ++i) {
    const int rn = i + RB - 1;          // next row to stage (tile-relative)
    const bool do_stage = (rn < NROWS);
    float sv[3];
    if (do_stage) stage_load(in1b, rn, y0t, x0t, t, sv);

    const float4 v4 = *reinterpret_cast<const float4*>(v2 + ((size_t)i * HH + y) * WW + x0);

    constexpr int NW = ((J + PX + 3) / 4) * 4;  // window floats (rounded to float4)
    #pragma unroll
    for (int c = 0; c < NC; ++c) {
      const float* rowp = &tile[c][rdslot][tx * PX + JC];
      float w[NW];
      #pragma unroll
      for (int k = 0; k < NW / 4; ++k) {
        const float4 q = *reinterpret_cast<const float4*>(rowp + 4 * k);
        w[4 * k + 0] = q.x; w[4 * k + 1] = q.y; w[4 * k + 2] = q.z; w[4 * k + 3] = q.w;
      }
      float hz0 = 0.f, hz1 = 0.f, hz2 = 0.f, hz3 = 0.f;
      #pragma unroll
      for (int j = 0; j < J; ++j) {
        hz0 = fmaf(w[j + 0], h4[j].x, hz0);
        hz1 = fmaf(w[j + 1], h4[j].y, hz1);
        hz2 = fmaf(w[j + 2], h4[j].z, hz2);
        hz3 = fmaf(w[j + 3], h4[j].w, hz3);
      }
      acc[c][0] = fmaf(v4.x, hz0, acc[c][0]);
      acc[c][1] = fmaf(v4.y, hz1, acc[c][1]);
      acc[c][2] = fmaf(v4.z, hz2, acc[c][2]);
      acc[c][3] = fmaf(v4.w, hz3, acc[c][3]);
    }

    if (do_stage) stage_store(tile, stslot, t, sv);
    __syncthreads();

    rdslot = (rdslot + 1 == RB) ? 0 : rdslot + 1;
    stslot = (stslot + 1 == RB) ? 0 : stslot + 1;
  }
}

__global__ __launch_bounds__(NTHREADS)
void sepconv_kernel(const float* __restrict__ in1, const float* __restrict__ in2,
                    const float* __restrict__ in3, float* __restrict__ out) {
  __shared__ lds_t tile;
  const int t = threadIdx.x;
  const int tx = t & (NTX - 1);
  const int ty = t >> 5;
  const int x0t = blockIdx.x * TW;
  const int y0t = blockIdx.y * TH;
  const int b = blockIdx.z;
  const int x0 = x0t + tx * PX;
  const int y = y0t + ty;

  const float* in1b = in1 + (size_t)b * NC * HP * WP;
  const float* v2 = in2 + (size_t)b * KFS * HH * WW;
  const float* h3 = in3 + (size_t)b * KFS * HH * WW;

  float acc[NC][PX];
  #pragma unroll
  for (int c = 0; c < NC; ++c)
    #pragma unroll
    for (int p = 0; p < PX; ++p) acc[c][p] = 0.f;

  run_pass<0, 28>(tile, in1b, v2, h3, acc, y, x0, y0t, x0t, tx, ty, t);
  run_pass<28, 23>(tile, in1b, v2, h3, acc, y, x0, y0t, x0t, tx, ty, t);

  float* outb = out + (size_t)b * NC * HH * WW;
  #pragma unroll
  for (int c = 0; c < NC; ++c) {
    float4 o;
    o.x = acc[c][0]; o.y = acc[c][1]; o.z = acc[c][2]; o.w = acc[c][3];
    *reinterpret_cast<float4*>(outb + ((size_t)c * HH + y) * WW + x0) = o;
  }
}

}  // namespace

extern "C" void kernel_launch(void* const* d_in, const int* in_sizes, int n_in,
                              void* d_out, int out_size, void* d_ws, size_t ws_size,
                              hipStream_t stream) {
  const float* in1 = (const float*)d_in[0];
  const float* in2 = (const float*)d_in[1];
  const float* in3 = (const float*)d_in[2];
  float* out = (float*)d_out;

  dim3 grid(WW / TW, HH / TH, NB);
  sepconv_kernel<<<grid, NTHREADS, 0, stream>>>(in1, in2, in3, out);
}